// Round 5
// baseline (5931.489 us; speedup 1.0000x reference)
//
#include <hip/hip_runtime.h>
#include <hip/hip_bf16.h>

// BasketballGNN: encoder MLP -> edge message MLP -> segment-mean -> update MLP -> tactical head.
// Inputs/outputs f32. Intermediate h in ws as f32 (mode 1) or bf16 (mode 0, if ws is small).
// Resubmission: rounds 3 & 4 both died on infra (UnresponsiveContainer) before the bench ran.

__device__ inline float bflo(unsigned u){ return __uint_as_float(u << 16); }
__device__ inline float bfhi(unsigned u){ return __uint_as_float(u & 0xffff0000u); }
__device__ inline unsigned short f2bu(float f){
  unsigned x = __float_as_uint(f);
  unsigned r = (x + 0x7fffu + ((x >> 16) & 1u)) >> 16;  // RNE
  return (unsigned short)r;
}
__device__ inline unsigned pck(float a, float b){ return (unsigned)f2bu(a) | ((unsigned)f2bu(b) << 16); }
__device__ inline void unpack8(uint4 v, float* f){
  f[0]=bflo(v.x); f[1]=bfhi(v.x); f[2]=bflo(v.y); f[3]=bfhi(v.y);
  f[4]=bflo(v.z); f[5]=bfhi(v.z); f[6]=bflo(v.w); f[7]=bfhi(v.w);
}

// ---------- Kernel F: detect edge-index width (int64 -> odd 32b words all zero) ----------
__global__ void k_flag(const int* __restrict__ ei, int* __restrict__ flag, int nwords)
{
  __shared__ int red[256];
  int acc = 0;
  for (int i = threadIdx.x; i < nwords; i += 256)
    if (i & 1) acc |= ei[i];
  red[threadIdx.x] = acc;
  __syncthreads();
  for (int s = 128; s > 0; s >>= 1){
    if (threadIdx.x < s) red[threadIdx.x] |= red[threadIdx.x + s];
    __syncthreads();
  }
  if (threadIdx.x == 0) flag[0] = (red[0] != 0) ? 1 : 0;  // 1 = int32, 0 = int64
}

// ---------------- Kernel A: node encoder  h = relu(x@W1+b1)@W2+b2 ----------------
__global__ __launch_bounds__(256, 2) void k_enc(
    const float* __restrict__ x,   // [N,6] f32
    const float* __restrict__ W1,  // [6,64]
    const float* __restrict__ b1,
    const float* __restrict__ W2,  // [64,64]
    const float* __restrict__ b2,
    float* __restrict__ hf,             // [N,64] f32 (mode 1)
    unsigned short* __restrict__ hb,    // [N,64] bf16 (mode 0)
    int N, int mode)
{
  __shared__ float W1s[6*64];
  __shared__ float W2s[64*64];
  __shared__ float b1s[64], b2s[64];
  int tid = threadIdx.x;
  for (int i = tid; i < 6*64; i += 256) W1s[i] = W1[i];
  for (int i = tid; i < 64*64; i += 256) W2s[i] = W2[i];
  if (tid < 64){ b1s[tid] = b1[tid]; b2s[tid] = b2[tid]; }
  __syncthreads();
  int n = blockIdx.x * 256 + tid;
  if (n >= N) return;

  float xv[6];
  #pragma unroll
  for (int k = 0; k < 6; k++) xv[k] = x[(size_t)n*6 + k];

  float acc[64];
  #pragma unroll
  for (int m = 0; m < 64; m++) acc[m] = b2s[m];

  #pragma unroll 1
  for (int j = 0; j < 64; j++){
    float s = b1s[j];
    #pragma unroll
    for (int k = 0; k < 6; k++) s += xv[k] * W1s[k*64 + j];
    s = fmaxf(s, 0.f);
    const float4* w2 = reinterpret_cast<const float4*>(&W2s[j*64]);
    #pragma unroll
    for (int q = 0; q < 16; q++){
      float4 w = w2[q];
      acc[4*q+0] += s*w.x; acc[4*q+1] += s*w.y; acc[4*q+2] += s*w.z; acc[4*q+3] += s*w.w;
    }
  }
  if (mode){
    float4* orow = reinterpret_cast<float4*>(hf + (size_t)n*64);
    #pragma unroll
    for (int q = 0; q < 16; q++){
      float4 v; v.x = acc[4*q+0]; v.y = acc[4*q+1]; v.z = acc[4*q+2]; v.w = acc[4*q+3];
      orow[q] = v;
    }
  } else {
    uint4* orow = reinterpret_cast<uint4*>(hb + (size_t)n*64);
    #pragma unroll
    for (int q = 0; q < 8; q++){
      uint4 v;
      v.x = pck(acc[8*q+0], acc[8*q+1]);
      v.y = pck(acc[8*q+2], acc[8*q+3]);
      v.z = pck(acc[8*q+4], acc[8*q+5]);
      v.w = pck(acc[8*q+6], acc[8*q+7]);
      orow[q] = v;
    }
  }
}

// ---------------- Kernel B: edge messages + atomic segment-sum ----------------
__global__ __launch_bounds__(256, 2) void k_edge(
    const float* __restrict__ hf,           // [N,64] f32 (mode 1)
    const unsigned short* __restrict__ hb,  // [N,64] bf16 (mode 0)
    const int* __restrict__ ei,             // [2,E] int32 OR int64 (see flag)
    const int* __restrict__ flag,
    const float* __restrict__ W1,  // [128,64]
    const float* __restrict__ b1,
    const float* __restrict__ W2,  // [64,64]
    const float* __restrict__ b2,
    float* __restrict__ sums,               // [N,64] f32 (zeroed)
    float* __restrict__ cnt,                // [N] f32 (zeroed)
    int E, int N, int mode)
{
  __shared__ float W1Ts[64*128];  // W1Ts[j][k] = W1[k][j]
  __shared__ float W2s[64*64];    // [j][m]
  __shared__ float b1s[64], b2s[64];
  int tid = threadIdx.x;
  for (int i = tid; i < 128*64; i += 256){
    int k = i >> 6, j = i & 63;
    W1Ts[j*128 + k] = W1[i];
  }
  for (int i = tid; i < 64*64; i += 256) W2s[i] = W2[i];
  if (tid < 64){ b1s[tid] = b1[tid]; b2s[tid] = b2[tid]; }
  __syncthreads();
  int e = blockIdx.x * 256 + tid;
  if (e >= E) return;

  int r, c;
  if (flag[0]){                       // int32 layout
    r = ei[e]; c = ei[(size_t)E + e];
  } else {                            // int64 layout: low word of each value
    r = ei[2*(size_t)e]; c = ei[2*((size_t)E + (size_t)e)];
  }
  r = min(max(r, 0), N-1); c = min(max(c, 0), N-1);

  float feat[128];
  if (mode){
    const float4* ha = reinterpret_cast<const float4*>(hf + (size_t)r*64);
    const float4* hc = reinterpret_cast<const float4*>(hf + (size_t)c*64);
    #pragma unroll
    for (int q = 0; q < 16; q++){
      float4 v = ha[q];
      feat[4*q+0]=v.x; feat[4*q+1]=v.y; feat[4*q+2]=v.z; feat[4*q+3]=v.w;
    }
    #pragma unroll
    for (int q = 0; q < 16; q++){
      float4 v = hc[q];
      feat[64+4*q+0]=v.x; feat[64+4*q+1]=v.y; feat[64+4*q+2]=v.z; feat[64+4*q+3]=v.w;
    }
  } else {
    const uint4* ha = reinterpret_cast<const uint4*>(hb + (size_t)r*64);
    const uint4* hc = reinterpret_cast<const uint4*>(hb + (size_t)c*64);
    #pragma unroll
    for (int q = 0; q < 8; q++) unpack8(ha[q], &feat[8*q]);       // full 64 bf16
    #pragma unroll
    for (int q = 0; q < 8; q++) unpack8(hc[q], &feat[64 + 8*q]);  // full 64 bf16
  }

  float msg[64];
  #pragma unroll
  for (int m = 0; m < 64; m++) msg[m] = b2s[m];

  #pragma unroll 1
  for (int j = 0; j < 64; j++){
    const float4* w1 = reinterpret_cast<const float4*>(&W1Ts[j*128]);
    float s0 = 0.f, s1 = 0.f, s2 = 0.f, s3 = 0.f;
    #pragma unroll
    for (int q = 0; q < 32; q++){
      float4 w = w1[q];
      s0 += feat[4*q+0]*w.x; s1 += feat[4*q+1]*w.y;
      s2 += feat[4*q+2]*w.z; s3 += feat[4*q+3]*w.w;
    }
    float s = fmaxf((s0+s1) + (s2+s3) + b1s[j], 0.f);
    const float4* w2 = reinterpret_cast<const float4*>(&W2s[j*64]);
    #pragma unroll
    for (int q = 0; q < 16; q++){
      float4 w = w2[q];
      msg[4*q+0] += s*w.x; msg[4*q+1] += s*w.y; msg[4*q+2] += s*w.z; msg[4*q+3] += s*w.w;
    }
  }
  float* srow = sums + (size_t)c*64;
  #pragma unroll
  for (int m = 0; m < 64; m++) atomicAdd(srow + m, msg[m]);
  atomicAdd(cnt + c, 1.0f);
}

// ---------------- Kernel C: mean + update MLP + tactical head ----------------
__global__ __launch_bounds__(256, 2) void k_upd(
    const float* __restrict__ hf,           // [N,64] f32 (mode 1)
    const unsigned short* __restrict__ hb,  // [N,64] bf16 (mode 0)
    const float* __restrict__ sums, const float* __restrict__ cnt,
    const float* __restrict__ uW1,   // [128,64]
    const float* __restrict__ ub1,
    const float* __restrict__ uW2,   // [64,32]
    const float* __restrict__ ub2,
    const float* __restrict__ tW1,   // [32,64]
    const float* __restrict__ tb1,
    const float* __restrict__ tW2,   // [64,16]
    const float* __restrict__ tb2,
    const float* __restrict__ tW3,   // [16,4]
    const float* __restrict__ tb3,
    float* __restrict__ out,          // [N*32] h2 then [N*4] tactical, f32
    int N, int mode)
{
  __shared__ float uW1Ts[64*128];  // [j][k]
  __shared__ float uW2s[64*32];
  __shared__ float tW1s[32*64];
  __shared__ float tW2s[64*16];
  __shared__ float tW3s[16*4];
  __shared__ float ub1s[64], ub2s[32], tb1s[64], tb2s[16], tb3s[4];
  int tid = threadIdx.x;
  for (int i = tid; i < 128*64; i += 256){ int k = i >> 6, j = i & 63; uW1Ts[j*128 + k] = uW1[i]; }
  for (int i = tid; i < 64*32; i += 256) uW2s[i] = uW2[i];
  for (int i = tid; i < 32*64; i += 256) tW1s[i] = tW1[i];
  for (int i = tid; i < 64*16; i += 256) tW2s[i] = tW2[i];
  if (tid < 64){ ub1s[tid] = ub1[tid]; tb1s[tid] = tb1[tid]; tW3s[tid] = tW3[tid]; }
  if (tid < 32) ub2s[tid] = ub2[tid];
  if (tid < 16) tb2s[tid] = tb2[tid];
  if (tid < 4)  tb3s[tid] = tb3[tid];
  __syncthreads();
  int n = blockIdx.x * 256 + tid;
  if (n >= N) return;

  float feat[128];
  if (mode){
    const float4* ha = reinterpret_cast<const float4*>(hf + (size_t)n*64);
    #pragma unroll
    for (int q = 0; q < 16; q++){
      float4 v = ha[q];
      feat[4*q+0]=v.x; feat[4*q+1]=v.y; feat[4*q+2]=v.z; feat[4*q+3]=v.w;
    }
  } else {
    const uint4* ha = reinterpret_cast<const uint4*>(hb + (size_t)n*64);
    #pragma unroll
    for (int q = 0; q < 8; q++) unpack8(ha[q], &feat[8*q]);  // full 64 bf16
  }

  float cf = cnt[n];
  float inv = (cf > 0.f) ? (1.0f / cf) : 0.f;  // where(count>0, sums/count, 0)
  const float4* sr = reinterpret_cast<const float4*>(sums + (size_t)n*64);
  #pragma unroll
  for (int q = 0; q < 16; q++){
    float4 v = sr[q];
    feat[64+4*q+0] = v.x*inv; feat[64+4*q+1] = v.y*inv;
    feat[64+4*q+2] = v.z*inv; feat[64+4*q+3] = v.w*inv;
  }

  float h2[32];
  #pragma unroll
  for (int m = 0; m < 32; m++) h2[m] = ub2s[m];

  #pragma unroll 1
  for (int j = 0; j < 64; j++){
    const float4* w1 = reinterpret_cast<const float4*>(&uW1Ts[j*128]);
    float s0 = 0.f, s1 = 0.f, s2 = 0.f, s3 = 0.f;
    #pragma unroll
    for (int q = 0; q < 32; q++){
      float4 w = w1[q];
      s0 += feat[4*q+0]*w.x; s1 += feat[4*q+1]*w.y;
      s2 += feat[4*q+2]*w.z; s3 += feat[4*q+3]*w.w;
    }
    float s = fmaxf((s0+s1) + (s2+s3) + ub1s[j], 0.f);
    const float4* w2 = reinterpret_cast<const float4*>(&uW2s[j*32]);
    #pragma unroll
    for (int q = 0; q < 8; q++){
      float4 w = w2[q];
      h2[4*q+0] += s*w.x; h2[4*q+1] += s*w.y; h2[4*q+2] += s*w.z; h2[4*q+3] += s*w.w;
    }
  }
  float4* o1 = reinterpret_cast<float4*>(out + (size_t)n*32);
  #pragma unroll
  for (int q = 0; q < 8; q++){
    float4 v;
    v.x = h2[4*q+0]; v.y = h2[4*q+1]; v.z = h2[4*q+2]; v.w = h2[4*q+3];
    o1[q] = v;
  }

  // tactical head: relu(h2@tW1+tb1) -> relu(@tW2+tb2) -> @tW3+tb3
  float t2[16];
  #pragma unroll
  for (int m = 0; m < 16; m++) t2[m] = 0.f;
  #pragma unroll 1
  for (int j = 0; j < 64; j++){
    float s = tb1s[j];
    #pragma unroll
    for (int k = 0; k < 32; k++) s += h2[k] * tW1s[k*64 + j];
    s = fmaxf(s, 0.f);
    #pragma unroll
    for (int m = 0; m < 16; m++) t2[m] += s * tW2s[j*16 + m];
  }
  float o[4];
  #pragma unroll
  for (int q = 0; q < 4; q++) o[q] = tb3s[q];
  #pragma unroll
  for (int m = 0; m < 16; m++){
    float tm = fmaxf(t2[m] + tb2s[m], 0.f);
    #pragma unroll
    for (int q = 0; q < 4; q++) o[q] += tm * tW3s[m*4 + q];
  }
  float4* o2 = reinterpret_cast<float4*>(out + (size_t)N*32 + (size_t)n*4);
  float4 vv; vv.x = o[0]; vv.y = o[1]; vv.z = o[2]; vv.w = o[3];
  *o2 = vv;
}

extern "C" void kernel_launch(void* const* d_in, const int* in_sizes, int n_in,
                              void* d_out, int out_size, void* d_ws, size_t ws_size,
                              hipStream_t stream)
{
  const float* x     = (const float*)d_in[0];
  const int*   ei    = (const int*)d_in[1];
  const float* encW1 = (const float*)d_in[2];
  const float* encb1 = (const float*)d_in[3];
  const float* encW2 = (const float*)d_in[4];
  const float* encb2 = (const float*)d_in[5];
  const float* msgW1 = (const float*)d_in[6];
  const float* msgb1 = (const float*)d_in[7];
  const float* msgW2 = (const float*)d_in[8];
  const float* msgb2 = (const float*)d_in[9];
  const float* updW1 = (const float*)d_in[10];
  const float* updb1 = (const float*)d_in[11];
  const float* updW2 = (const float*)d_in[12];
  const float* updb2 = (const float*)d_in[13];
  const float* tacW1 = (const float*)d_in[14];
  const float* tacb1 = (const float*)d_in[15];
  const float* tacW2 = (const float*)d_in[16];
  const float* tacb2 = (const float*)d_in[17];
  const float* tacW3 = (const float*)d_in[18];
  const float* tacb3 = (const float*)d_in[19];

  int N = in_sizes[0] / 6;
  int E = in_sizes[1] / 2;
  float* out = (float*)d_out;

  // ws layout. mode 1: h as f32 [N*64] | sums f32 [N*64] | cnt [N] | flag
  //            mode 0: h as bf16 [N*64] | sums f32 [N*64] | cnt [N] | flag
  size_t hf_bytes = (size_t)N * 64 * 4;
  size_t hb_bytes = (size_t)N * 64 * 2;
  size_t tail     = (size_t)N * 64 * 4 + (size_t)N * 4 + 4;   // sums + cnt + flag
  int mode = (ws_size >= hf_bytes + tail + 256) ? 1 : 0;

  char* ws = (char*)d_ws;
  float* hf = (float*)ws;
  unsigned short* hb = (unsigned short*)ws;
  size_t hsz  = mode ? hf_bytes : hb_bytes;
  size_t offS = (hsz + 255) & ~(size_t)255;
  float* sums = (float*)(ws + offS);
  float* cnt  = (float*)(ws + offS + (size_t)N * 64 * 4);
  int*  flag  = (int*)(ws + offS + (size_t)N * 64 * 4 + (size_t)N * 4);

  hipMemsetAsync(ws + offS, 0, (size_t)N * 64 * 4 + (size_t)N * 4 + 4, stream);

  dim3 blk(256);
  k_flag<<<dim3(1), blk, 0, stream>>>(ei, flag, 8192);
  k_enc<<<dim3((N + 255) / 256), blk, 0, stream>>>(x, encW1, encb1, encW2, encb2, hf, hb, N, mode);
  k_edge<<<dim3((E + 255) / 256), blk, 0, stream>>>(hf, hb, ei, flag,
                                                    msgW1, msgb1, msgW2, msgb2,
                                                    sums, cnt, E, N, mode);
  k_upd<<<dim3((N + 255) / 256), blk, 0, stream>>>(hf, hb, sums, cnt,
                                                   updW1, updb1, updW2, updb2,
                                                   tacW1, tacb1, tacW2, tacb2, tacW3, tacb3,
                                                   out, N, mode);
}

// Round 6
// 1183.778 us; speedup vs baseline: 5.0106x; 5.0106x over previous
//
#include <hip/hip_runtime.h>
#include <hip/hip_bf16.h>

// BasketballGNN, CSR-aggregation version.
// R5 evidence: 64 f32 atomicAdd/edge = 3.25GB memory-side writes, atomic-throughput-bound
// (VALUBusy 9%). This version: CSR build (int atomics only) + wave-per-node recompute
// aggregation with zero float atomics. h stored bf16.

__device__ inline float bflo(unsigned u){ return __uint_as_float(u << 16); }
__device__ inline float bfhi(unsigned u){ return __uint_as_float(u & 0xffff0000u); }
__device__ inline unsigned short f2bu(float f){
  unsigned x = __float_as_uint(f);
  unsigned r = (x + 0x7fffu + ((x >> 16) & 1u)) >> 16;  // RNE
  return (unsigned short)r;
}
__device__ inline unsigned pck(float a, float b){ return (unsigned)f2bu(a) | ((unsigned)f2bu(b) << 16); }
__device__ inline void unpack8(uint4 v, float* f){
  f[0]=bflo(v.x); f[1]=bfhi(v.x); f[2]=bflo(v.y); f[3]=bfhi(v.y);
  f[4]=bflo(v.z); f[5]=bfhi(v.z); f[6]=bflo(v.w); f[7]=bfhi(v.w);
}

// ---------- detect edge-index width (int64 -> odd 32b words all zero) ----------
__global__ void k_flag(const int* __restrict__ ei, int* __restrict__ flag, int nwords)
{
  __shared__ int red[256];
  int acc = 0;
  for (int i = threadIdx.x; i < nwords; i += 256)
    if (i & 1) acc |= ei[i];
  red[threadIdx.x] = acc;
  __syncthreads();
  for (int s = 128; s > 0; s >>= 1){
    if (threadIdx.x < s) red[threadIdx.x] |= red[threadIdx.x + s];
    __syncthreads();
  }
  if (threadIdx.x == 0) flag[0] = (red[0] != 0) ? 1 : 0;  // 1 = int32, 0 = int64
}

__device__ inline void load_rc(const int* ei, const int* flag, int e, int E, int N, int& r, int& c){
  if (flag[0]){ r = ei[e]; c = ei[(size_t)E + e]; }
  else        { r = ei[2*(size_t)e]; c = ei[2*((size_t)E + (size_t)e)]; }
  r = min(max(r, 0), N-1); c = min(max(c, 0), N-1);
}

// ---------------- node encoder  h = relu(x@W1+b1)@W2+b2 -> bf16 ----------------
__global__ __launch_bounds__(256, 2) void k_enc(
    const float* __restrict__ x,   // [N,6]
    const float* __restrict__ W1,  // [6,64]
    const float* __restrict__ b1,
    const float* __restrict__ W2,  // [64,64]
    const float* __restrict__ b2,
    unsigned short* __restrict__ hb,  // [N,64] bf16
    int N)
{
  __shared__ float W1s[6*64];
  __shared__ float W2s[64*64];
  __shared__ float b1s[64], b2s[64];
  int tid = threadIdx.x;
  for (int i = tid; i < 6*64; i += 256) W1s[i] = W1[i];
  for (int i = tid; i < 64*64; i += 256) W2s[i] = W2[i];
  if (tid < 64){ b1s[tid] = b1[tid]; b2s[tid] = b2[tid]; }
  __syncthreads();
  int n = blockIdx.x * 256 + tid;
  if (n >= N) return;

  float xv[6];
  #pragma unroll
  for (int k = 0; k < 6; k++) xv[k] = x[(size_t)n*6 + k];

  float acc[64];
  #pragma unroll
  for (int m = 0; m < 64; m++) acc[m] = b2s[m];

  #pragma unroll 1
  for (int j = 0; j < 64; j++){
    float s = b1s[j];
    #pragma unroll
    for (int k = 0; k < 6; k++) s += xv[k] * W1s[k*64 + j];
    s = fmaxf(s, 0.f);
    const float4* w2 = reinterpret_cast<const float4*>(&W2s[j*64]);
    #pragma unroll
    for (int q = 0; q < 16; q++){
      float4 w = w2[q];
      acc[4*q+0] += s*w.x; acc[4*q+1] += s*w.y; acc[4*q+2] += s*w.z; acc[4*q+3] += s*w.w;
    }
  }
  uint4* orow = reinterpret_cast<uint4*>(hb + (size_t)n*64);
  #pragma unroll
  for (int q = 0; q < 8; q++){
    uint4 v;
    v.x = pck(acc[8*q+0], acc[8*q+1]);
    v.y = pck(acc[8*q+2], acc[8*q+3]);
    v.z = pck(acc[8*q+4], acc[8*q+5]);
    v.w = pck(acc[8*q+6], acc[8*q+7]);
    orow[q] = v;
  }
}

// ---------------- CSR build ----------------
__global__ void k_cnt(const int* __restrict__ ei, const int* __restrict__ flag,
                      int* __restrict__ counts, int E, int N)
{
  int e = blockIdx.x*256 + threadIdx.x;
  if (e >= E) return;
  int r, c; load_rc(ei, flag, e, E, N, r, c);
  atomicAdd(&counts[c], 1);
}

// block-local exclusive scan (256/block), emit block sums
__global__ void k_scan1(const int* __restrict__ counts, int* __restrict__ offsets,
                        int* __restrict__ part, int N)
{
  __shared__ int tmp[256];
  int t = threadIdx.x;
  int i = blockIdx.x*256 + t;
  int v = (i < N) ? counts[i] : 0;
  tmp[t] = v;
  __syncthreads();
  for (int d = 1; d < 256; d <<= 1){
    int y = (t >= d) ? tmp[t-d] : 0;
    __syncthreads();
    tmp[t] += y;
    __syncthreads();
  }
  if (i < N) offsets[i] = tmp[t] - v;           // block-local exclusive
  if (t == 255) part[blockIdx.x] = tmp[255];    // block total
}

// exclusive scan of block sums (single block; nblk <= 256)
__global__ void k_scan2(int* __restrict__ part, int nblk)
{
  __shared__ int tmp[256];
  int t = threadIdx.x;
  int v = (t < nblk) ? part[t] : 0;
  tmp[t] = v;
  __syncthreads();
  for (int d = 1; d < 256; d <<= 1){
    int y = (t >= d) ? tmp[t-d] : 0;
    __syncthreads();
    tmp[t] += y;
    __syncthreads();
  }
  if (t < nblk) part[t] = tmp[t] - v;           // exclusive
}

__global__ void k_scan3(const int* __restrict__ counts, int* __restrict__ offsets,
                        int* __restrict__ cursor, const int* __restrict__ part, int N)
{
  int i = blockIdx.x*256 + threadIdx.x;
  if (i >= N) return;
  int o = offsets[i] + part[blockIdx.x];
  offsets[i] = o;
  cursor[i]  = o;
  if (i == N-1) offsets[N] = o + counts[i];
}

__global__ void k_fill(const int* __restrict__ ei, const int* __restrict__ flag,
                       int* __restrict__ cursor, int* __restrict__ list, int E, int N)
{
  int e = blockIdx.x*256 + threadIdx.x;
  if (e >= E) return;
  int r, c; load_rc(ei, flag, e, E, N, r, c);
  int pos = atomicAdd(&cursor[c], 1);
  list[pos] = r;   // store source node directly
}

// ---------------- aggregation: wave-per-node, recompute edge MLP, no atomics ----------------
// lane j computes hidden unit j (MLP1); same lane as feature m accumulates MLP2 output.
// s-vector exchanged via per-wave LDS slice (in-wave DS ops are in-order; no barrier).
__global__ __launch_bounds__(256, 2) void k_agg(
    const unsigned short* __restrict__ hb,  // [N,64] bf16
    const int* __restrict__ offsets,        // [N+1]
    const int* __restrict__ list,           // [E] source node per dest-grouped slot
    const float* __restrict__ W1,           // [128,64]
    const float* __restrict__ b1,
    const float* __restrict__ W2,           // [64,64]
    const float* __restrict__ b2,
    float* __restrict__ aggf,               // [N,64] f32 mean (aggF32)
    unsigned short* __restrict__ aggh,      // [N,64] bf16 mean (else)
    int N, int aggF32)
{
  __shared__ float sS[4][64];
  int tid  = threadIdx.x;
  int lane = tid & 63;
  int w    = tid >> 6;

  // per-lane weight registers (statically indexed via unrolled loops)
  float w1lo[64], w1hi[64], w2c[64];
  #pragma unroll
  for (int k = 0; k < 64; k++) w1lo[k] = W1[k*64 + lane];        // feat = [h[row]; h[col]]
  #pragma unroll
  for (int k = 0; k < 64; k++) w1hi[k] = W1[(64+k)*64 + lane];
  #pragma unroll
  for (int j = 0; j < 64; j++) w2c[j] = W2[j*64 + lane];
  float b1l = b1[lane], b2l = b2[lane];

  for (int node = blockIdx.x*4 + w; node < N; node += gridDim.x*4){
    int nodeU = __builtin_amdgcn_readfirstlane(node);
    int base  = offsets[nodeU];
    int deg   = offsets[nodeU+1] - base;

    // hc contribution to every hidden unit (fixed per node)
    const unsigned* hcp = reinterpret_cast<const unsigned*>(hb + (size_t)nodeU*64);
    float sc = 0.f;
    #pragma unroll
    for (int q = 0; q < 32; q++){
      unsigned u = hcp[q];
      sc += bflo(u)*w1hi[2*q] + bfhi(u)*w1hi[2*q+1];
    }

    float acc = 0.f;
    for (int s = 0; s < deg; s++){
      int r = __builtin_amdgcn_readfirstlane(list[base + s]);
      const unsigned* hrp = reinterpret_cast<const unsigned*>(hb + (size_t)r*64);
      unsigned cur[32];
      #pragma unroll
      for (int q = 0; q < 32; q++) cur[q] = hrp[q];

      float sj = sc + b1l;
      #pragma unroll
      for (int q = 0; q < 32; q++)
        sj += bflo(cur[q])*w1lo[2*q] + bfhi(cur[q])*w1lo[2*q+1];
      sj = fmaxf(sj, 0.f);

      sS[w][lane] = sj;  // in-wave write; DS ops complete in order
      const float4* s4 = reinterpret_cast<const float4*>(&sS[w][0]);
      float m = b2l;
      #pragma unroll
      for (int q = 0; q < 16; q++){
        float4 v = s4[q];  // broadcast read (same addr across lanes)
        m += v.x*w2c[4*q+0] + v.y*w2c[4*q+1] + v.z*w2c[4*q+2] + v.w*w2c[4*q+3];
      }
      acc += m;
    }
    float inv = (deg > 0) ? (1.0f/(float)deg) : 0.f;
    acc *= inv;
    if (aggF32) aggf[(size_t)node*64 + lane] = acc;
    else        aggh[(size_t)node*64 + lane] = f2bu(acc);
  }
}

// ---------------- mean + update MLP + tactical head ----------------
__global__ __launch_bounds__(256, 2) void k_upd(
    const unsigned short* __restrict__ hb,  // [N,64] bf16
    const float* __restrict__ aggf,
    const unsigned short* __restrict__ aggh,
    const float* __restrict__ uW1,   // [128,64]
    const float* __restrict__ ub1,
    const float* __restrict__ uW2,   // [64,32]
    const float* __restrict__ ub2,
    const float* __restrict__ tW1,   // [32,64]
    const float* __restrict__ tb1,
    const float* __restrict__ tW2,   // [64,16]
    const float* __restrict__ tb2,
    const float* __restrict__ tW3,   // [16,4]
    const float* __restrict__ tb3,
    float* __restrict__ out,          // [N*32] h2 then [N*4] tactical
    int N, int aggF32)
{
  __shared__ float uW1Ts[64*128];  // [j][k]
  __shared__ float uW2s[64*32];
  __shared__ float tW1s[32*64];
  __shared__ float tW2s[64*16];
  __shared__ float tW3s[16*4];
  __shared__ float ub1s[64], ub2s[32], tb1s[64], tb2s[16], tb3s[4];
  int tid = threadIdx.x;
  for (int i = tid; i < 128*64; i += 256){ int k = i >> 6, j = i & 63; uW1Ts[j*128 + k] = uW1[i]; }
  for (int i = tid; i < 64*32; i += 256) uW2s[i] = uW2[i];
  for (int i = tid; i < 32*64; i += 256) tW1s[i] = tW1[i];
  for (int i = tid; i < 64*16; i += 256) tW2s[i] = tW2[i];
  if (tid < 64){ ub1s[tid] = ub1[tid]; tb1s[tid] = tb1[tid]; tW3s[tid] = tW3[tid]; }
  if (tid < 32) ub2s[tid] = ub2[tid];
  if (tid < 16) tb2s[tid] = tb2[tid];
  if (tid < 4)  tb3s[tid] = tb3[tid];
  __syncthreads();
  int n = blockIdx.x * 256 + tid;
  if (n >= N) return;

  float feat[128];
  {
    const uint4* ha = reinterpret_cast<const uint4*>(hb + (size_t)n*64);
    #pragma unroll
    for (int q = 0; q < 8; q++) unpack8(ha[q], &feat[8*q]);
  }
  if (aggF32){
    const float4* sr = reinterpret_cast<const float4*>(aggf + (size_t)n*64);
    #pragma unroll
    for (int q = 0; q < 16; q++){
      float4 v = sr[q];
      feat[64+4*q+0]=v.x; feat[64+4*q+1]=v.y; feat[64+4*q+2]=v.z; feat[64+4*q+3]=v.w;
    }
  } else {
    const uint4* sr = reinterpret_cast<const uint4*>(aggh + (size_t)n*64);
    #pragma unroll
    for (int q = 0; q < 8; q++) unpack8(sr[q], &feat[64+8*q]);
  }

  float h2[32];
  #pragma unroll
  for (int m = 0; m < 32; m++) h2[m] = ub2s[m];

  #pragma unroll 1
  for (int j = 0; j < 64; j++){
    const float4* w1 = reinterpret_cast<const float4*>(&uW1Ts[j*128]);
    float s0 = 0.f, s1 = 0.f, s2 = 0.f, s3 = 0.f;
    #pragma unroll
    for (int q = 0; q < 32; q++){
      float4 w = w1[q];
      s0 += feat[4*q+0]*w.x; s1 += feat[4*q+1]*w.y;
      s2 += feat[4*q+2]*w.z; s3 += feat[4*q+3]*w.w;
    }
    float s = fmaxf((s0+s1) + (s2+s3) + ub1s[j], 0.f);
    const float4* w2 = reinterpret_cast<const float4*>(&uW2s[j*32]);
    #pragma unroll
    for (int q = 0; q < 8; q++){
      float4 w = w2[q];
      h2[4*q+0] += s*w.x; h2[4*q+1] += s*w.y; h2[4*q+2] += s*w.z; h2[4*q+3] += s*w.w;
    }
  }
  float4* o1 = reinterpret_cast<float4*>(out + (size_t)n*32);
  #pragma unroll
  for (int q = 0; q < 8; q++){
    float4 v;
    v.x = h2[4*q+0]; v.y = h2[4*q+1]; v.z = h2[4*q+2]; v.w = h2[4*q+3];
    o1[q] = v;
  }

  float t2[16];
  #pragma unroll
  for (int m = 0; m < 16; m++) t2[m] = 0.f;
  #pragma unroll 1
  for (int j = 0; j < 64; j++){
    float s = tb1s[j];
    #pragma unroll
    for (int k = 0; k < 32; k++) s += h2[k] * tW1s[k*64 + j];
    s = fmaxf(s, 0.f);
    #pragma unroll
    for (int m = 0; m < 16; m++) t2[m] += s * tW2s[j*16 + m];
  }
  float o[4];
  #pragma unroll
  for (int q = 0; q < 4; q++) o[q] = tb3s[q];
  #pragma unroll
  for (int m = 0; m < 16; m++){
    float tm = fmaxf(t2[m] + tb2s[m], 0.f);
    #pragma unroll
    for (int q = 0; q < 4; q++) o[q] += tm * tW3s[m*4 + q];
  }
  float4* o2 = reinterpret_cast<float4*>(out + (size_t)N*32 + (size_t)n*4);
  float4 vv; vv.x = o[0]; vv.y = o[1]; vv.z = o[2]; vv.w = o[3];
  *o2 = vv;
}

extern "C" void kernel_launch(void* const* d_in, const int* in_sizes, int n_in,
                              void* d_out, int out_size, void* d_ws, size_t ws_size,
                              hipStream_t stream)
{
  const float* x     = (const float*)d_in[0];
  const int*   ei    = (const int*)d_in[1];
  const float* encW1 = (const float*)d_in[2];
  const float* encb1 = (const float*)d_in[3];
  const float* encW2 = (const float*)d_in[4];
  const float* encb2 = (const float*)d_in[5];
  const float* msgW1 = (const float*)d_in[6];
  const float* msgb1 = (const float*)d_in[7];
  const float* msgW2 = (const float*)d_in[8];
  const float* msgb2 = (const float*)d_in[9];
  const float* updW1 = (const float*)d_in[10];
  const float* updb1 = (const float*)d_in[11];
  const float* updW2 = (const float*)d_in[12];
  const float* updb2 = (const float*)d_in[13];
  const float* tacW1 = (const float*)d_in[14];
  const float* tacb1 = (const float*)d_in[15];
  const float* tacW2 = (const float*)d_in[16];
  const float* tacb2 = (const float*)d_in[17];
  const float* tacW3 = (const float*)d_in[18];
  const float* tacb3 = (const float*)d_in[19];

  int N = in_sizes[0] / 6;
  int E = in_sizes[1] / 2;
  float* out = (float*)d_out;

  // ws layout (256B aligned chunks):
  // hb [N*64 bf16] | agg (f32 or bf16) | counts [N] | offsets [N+1] | cursor [N] | part [256] | list [E] | flag
  auto align = [](size_t v){ return (v + 255) & ~(size_t)255; };
  size_t o_hb   = 0;
  size_t o_aggE = align(o_hb + (size_t)N*64*2);
  size_t aggF32Bytes = (size_t)N*64*4, aggBf;
  // totals for mode decision
  size_t restBytes = align((size_t)N*4) /*counts*/;
  // compute rest chain once with placeholder; easier: explicit
  auto total_with = [&](size_t aggBytes){
    size_t o = o_aggE + aggBytes;
    o = align(o); o += (size_t)N*4;          // counts
    o = align(o); o += (size_t)(N+1)*4;      // offsets
    o = align(o); o += (size_t)N*4;          // cursor
    o = align(o); o += 256*4;                // part
    o = align(o); o += (size_t)E*4;          // list
    o = align(o); o += 4;                    // flag
    return o;
  };
  (void)restBytes; (void)aggBf;
  int aggF32 = (ws_size >= total_with(aggF32Bytes)) ? 1 : 0;
  size_t aggBytes = aggF32 ? aggF32Bytes : (size_t)N*64*2;

  char* ws = (char*)d_ws;
  size_t o = o_aggE;
  float*          aggf   = (float*)(ws + o);
  unsigned short* aggh   = (unsigned short*)(ws + o);
  o = align(o + aggBytes);
  int* counts  = (int*)(ws + o); o = align(o + (size_t)N*4);
  int* offsets = (int*)(ws + o); o = align(o + (size_t)(N+1)*4);
  int* cursor  = (int*)(ws + o); o = align(o + (size_t)N*4);
  int* part    = (int*)(ws + o); o = align(o + 256*4);
  int* list    = (int*)(ws + o); o = align(o + (size_t)E*4);
  int* flag    = (int*)(ws + o);
  unsigned short* hb = (unsigned short*)(ws + o_hb);

  hipMemsetAsync(counts, 0, (size_t)N*4, stream);

  dim3 blk(256);
  int nblkN = (N + 255) / 256;       // 196 for 50k (<=256 required by k_scan2)
  int nblkE = (E + 255) / 256;

  k_flag <<<dim3(1),     blk, 0, stream>>>(ei, flag, 8192);
  k_enc  <<<dim3(nblkN), blk, 0, stream>>>(x, encW1, encb1, encW2, encb2, hb, N);
  k_cnt  <<<dim3(nblkE), blk, 0, stream>>>(ei, flag, counts, E, N);
  k_scan1<<<dim3(nblkN), blk, 0, stream>>>(counts, offsets, part, N);
  k_scan2<<<dim3(1),     blk, 0, stream>>>(part, nblkN);
  k_scan3<<<dim3(nblkN), blk, 0, stream>>>(counts, offsets, cursor, part, N);
  k_fill <<<dim3(nblkE), blk, 0, stream>>>(ei, flag, cursor, list, E, N);
  k_agg  <<<dim3(2048),  blk, 0, stream>>>(hb, offsets, list,
                                           msgW1, msgb1, msgW2, msgb2,
                                           aggf, aggh, N, aggF32);
  k_upd  <<<dim3(nblkN), blk, 0, stream>>>(hb, aggf, aggh,
                                           updW1, updb1, updW2, updb2,
                                           tacW1, tacb1, tacW2, tacb2, tacW3, tacb3,
                                           out, N, aggF32);
}

// Round 8
// 441.972 us; speedup vs baseline: 13.4205x; 2.6784x over previous
//
#include <hip/hip_runtime.h>
#include <hip/hip_bf16.h>

// BasketballGNN, factored-aggregation version (resubmit: R7 died on infra).
// msg_e = W2^T relu(u[r]+v[c]+b1) + b2 with u,v per NODE; per-edge work = gather+relu-acc.

__device__ inline float bflo(unsigned u){ return __uint_as_float(u << 16); }
__device__ inline float bfhi(unsigned u){ return __uint_as_float(u & 0xffff0000u); }
__device__ inline float gbf(const unsigned short* p){ return __uint_as_float(((unsigned)(*p)) << 16); }
__device__ inline unsigned short f2bu(float f){
  unsigned x = __float_as_uint(f);
  unsigned r = (x + 0x7fffu + ((x >> 16) & 1u)) >> 16;  // RNE
  return (unsigned short)r;
}
__device__ inline unsigned pck(float a, float b){ return (unsigned)f2bu(a) | ((unsigned)f2bu(b) << 16); }
__device__ inline void unpack8(uint4 v, float* f){
  f[0]=bflo(v.x); f[1]=bfhi(v.x); f[2]=bflo(v.y); f[3]=bfhi(v.y);
  f[4]=bflo(v.z); f[5]=bfhi(v.z); f[6]=bflo(v.w); f[7]=bfhi(v.w);
}

// ---------- detect edge-index width (int64 -> odd 32b words all zero) ----------
__global__ void k_flag(const int* __restrict__ ei, int* __restrict__ flag, int nwords)
{
  __shared__ int red[256];
  int acc = 0;
  for (int i = threadIdx.x; i < nwords; i += 256)
    if (i & 1) acc |= ei[i];
  red[threadIdx.x] = acc;
  __syncthreads();
  for (int s = 128; s > 0; s >>= 1){
    if (threadIdx.x < s) red[threadIdx.x] |= red[threadIdx.x + s];
    __syncthreads();
  }
  if (threadIdx.x == 0) flag[0] = (red[0] != 0) ? 1 : 0;  // 1 = int32, 0 = int64
}

__device__ inline void load_rc(const int* ei, const int* flag, int e, int E, int N, int& r, int& c){
  if (flag[0]){ r = ei[e]; c = ei[(size_t)E + e]; }
  else        { r = ei[2*(size_t)e]; c = ei[2*((size_t)E + (size_t)e)]; }
  r = min(max(r, 0), N-1); c = min(max(c, 0), N-1);
}

// ---------------- node encoder  h = relu(x@W1+b1)@W2+b2 -> bf16 ----------------
__global__ __launch_bounds__(256, 2) void k_enc(
    const float* __restrict__ x,   // [N,6]
    const float* __restrict__ W1,  // [6,64]
    const float* __restrict__ b1,
    const float* __restrict__ W2,  // [64,64]
    const float* __restrict__ b2,
    unsigned short* __restrict__ hb,  // [N,64] bf16
    int N)
{
  __shared__ float W1s[6*64];
  __shared__ float W2s[64*64];
  __shared__ float b1s[64], b2s[64];
  int tid = threadIdx.x;
  for (int i = tid; i < 6*64; i += 256) W1s[i] = W1[i];
  for (int i = tid; i < 64*64; i += 256) W2s[i] = W2[i];
  if (tid < 64){ b1s[tid] = b1[tid]; b2s[tid] = b2[tid]; }
  __syncthreads();
  int n = blockIdx.x * 256 + tid;
  if (n >= N) return;

  float xv[6];
  #pragma unroll
  for (int k = 0; k < 6; k++) xv[k] = x[(size_t)n*6 + k];

  float acc[64];
  #pragma unroll
  for (int m = 0; m < 64; m++) acc[m] = b2s[m];

  #pragma unroll 1
  for (int j = 0; j < 64; j++){
    float s = b1s[j];
    #pragma unroll
    for (int k = 0; k < 6; k++) s += xv[k] * W1s[k*64 + j];
    s = fmaxf(s, 0.f);
    const float4* w2 = reinterpret_cast<const float4*>(&W2s[j*64]);
    #pragma unroll
    for (int q = 0; q < 16; q++){
      float4 w = w2[q];
      acc[4*q+0] += s*w.x; acc[4*q+1] += s*w.y; acc[4*q+2] += s*w.z; acc[4*q+3] += s*w.w;
    }
  }
  uint4* orow = reinterpret_cast<uint4*>(hb + (size_t)n*64);
  #pragma unroll
  for (int q = 0; q < 8; q++){
    uint4 v;
    v.x = pck(acc[8*q+0], acc[8*q+1]);
    v.y = pck(acc[8*q+2], acc[8*q+3]);
    v.z = pck(acc[8*q+4], acc[8*q+5]);
    v.w = pck(acc[8*q+6], acc[8*q+7]);
    orow[q] = v;
  }
}

// ---------------- u,v precompute: u = W1[:64]^T h, v = W1[64:]^T h (wave-per-node) ----------------
template<int PREC>
__global__ __launch_bounds__(256) void k_uv(
    const unsigned short* __restrict__ hb,  // [N,64] bf16
    const float* __restrict__ W1,           // [128,64]
    float* __restrict__ uf, unsigned short* __restrict__ uh,
    float* __restrict__ vf, unsigned short* __restrict__ vh,
    int N)
{
  int lane = threadIdx.x & 63, w = threadIdx.x >> 6;
  float w1lo[64], w1hi[64];
  #pragma unroll
  for (int k = 0; k < 64; k++) w1lo[k] = W1[k*64 + lane];
  #pragma unroll
  for (int k = 0; k < 64; k++) w1hi[k] = W1[(64+k)*64 + lane];

  for (int node = blockIdx.x*4 + w; node < N; node += gridDim.x*4){
    const unsigned* hp = reinterpret_cast<const unsigned*>(hb + (size_t)node*64);
    unsigned cur[32];
    #pragma unroll
    for (int q = 0; q < 32; q++) cur[q] = hp[q];
    float su = 0.f, sv = 0.f;
    #pragma unroll
    for (int q = 0; q < 32; q++){
      float a = bflo(cur[q]), b = bfhi(cur[q]);
      su += a*w1lo[2*q] + b*w1lo[2*q+1];
      sv += a*w1hi[2*q] + b*w1hi[2*q+1];
    }
    if (PREC){ uf[(size_t)node*64 + lane] = su; vf[(size_t)node*64 + lane] = sv; }
    else     { uh[(size_t)node*64 + lane] = f2bu(su); vh[(size_t)node*64 + lane] = f2bu(sv); }
  }
}

// ---------------- CSR build ----------------
__global__ void k_cnt(const int* __restrict__ ei, const int* __restrict__ flag,
                      int* __restrict__ counts, int E, int N)
{
  int e = blockIdx.x*256 + threadIdx.x;
  if (e >= E) return;
  int r, c; load_rc(ei, flag, e, E, N, r, c);
  atomicAdd(&counts[c], 1);
}

__global__ void k_scan1(const int* __restrict__ counts, int* __restrict__ offsets,
                        int* __restrict__ part, int N)
{
  __shared__ int tmp[256];
  int t = threadIdx.x;
  int i = blockIdx.x*256 + t;
  int v = (i < N) ? counts[i] : 0;
  tmp[t] = v;
  __syncthreads();
  for (int d = 1; d < 256; d <<= 1){
    int y = (t >= d) ? tmp[t-d] : 0;
    __syncthreads();
    tmp[t] += y;
    __syncthreads();
  }
  if (i < N) offsets[i] = tmp[t] - v;           // block-local exclusive
  if (t == 255) part[blockIdx.x] = tmp[255];    // block total
}

// exclusive scan of block sums (single block; nblk <= 256); also offsets[N] = E
__global__ void k_scan2(int* __restrict__ part, int nblk, int* __restrict__ offsets, int N, int E)
{
  __shared__ int tmp[256];
  int t = threadIdx.x;
  int v = (t < nblk) ? part[t] : 0;
  tmp[t] = v;
  __syncthreads();
  for (int d = 1; d < 256; d <<= 1){
    int y = (t >= d) ? tmp[t-d] : 0;
    __syncthreads();
    tmp[t] += y;
    __syncthreads();
  }
  if (t < nblk) part[t] = tmp[t] - v;           // exclusive
  if (t == 0) offsets[N] = E;
}

// add block prefix; init cursor (cursor aliases counts: counts dead after scan1)
__global__ void k_scan3(int* __restrict__ offsets, int* cursor, const int* __restrict__ part, int N)
{
  int i = blockIdx.x*256 + threadIdx.x;
  if (i >= N) return;
  int o = offsets[i] + part[blockIdx.x];
  offsets[i] = o;
  cursor[i]  = o;
}

__global__ void k_fill(const int* __restrict__ ei, const int* __restrict__ flag,
                       int* cursor, int* __restrict__ list, int E, int N)
{
  int e = blockIdx.x*256 + threadIdx.x;
  if (e >= E) return;
  int r, c; load_rc(ei, flag, e, E, N, r, c);
  int pos = atomicAdd(&cursor[c], 1);
  list[pos] = r;   // source node per dest-grouped slot
}

// ---------------- aggregation: wave-per-node; per edge = gather u[r] + relu-acc ----------------
// agg output may alias v (each node's v row read only by its owner wave, before agg write).
template<int PREC>
__global__ __launch_bounds__(256) void k_agg(
    const float* __restrict__ uf, const unsigned short* __restrict__ uh,
    const float* vfin, const unsigned short* vhin,
    float* aggf, unsigned short* aggh,
    const float* __restrict__ b1,
    const float* __restrict__ W2,   // [64,64]
    const float* __restrict__ b2,
    const int* __restrict__ offsets, const int* __restrict__ list, int N)
{
  __shared__ float sS[4][64];
  int lane = threadIdx.x & 63, w = threadIdx.x >> 6;
  float w2c[64];
  #pragma unroll
  for (int j = 0; j < 64; j++) w2c[j] = W2[j*64 + lane];
  float b1l = b1[lane], b2l = b2[lane];

  for (int node = blockIdx.x*4 + w; node < N; node += gridDim.x*4){
    int base = offsets[node];
    int deg  = offsets[node+1] - base;
    float vc = (PREC ? vfin[(size_t)node*64 + lane]
                     : gbf(vhin + (size_t)node*64 + lane)) + b1l;

    float acc = 0.f;
    int s = 0;
    for (; s + 4 <= deg; s += 4){
      int r0 = list[base+s+0], r1 = list[base+s+1];
      int r2 = list[base+s+2], r3 = list[base+s+3];
      float z0 = PREC ? uf[(size_t)r0*64 + lane] : gbf(uh + (size_t)r0*64 + lane);
      float z1 = PREC ? uf[(size_t)r1*64 + lane] : gbf(uh + (size_t)r1*64 + lane);
      float z2 = PREC ? uf[(size_t)r2*64 + lane] : gbf(uh + (size_t)r2*64 + lane);
      float z3 = PREC ? uf[(size_t)r3*64 + lane] : gbf(uh + (size_t)r3*64 + lane);
      acc += fmaxf(z0+vc, 0.f) + fmaxf(z1+vc, 0.f) + fmaxf(z2+vc, 0.f) + fmaxf(z3+vc, 0.f);
    }
    for (; s < deg; s++){
      int r = list[base+s];
      float z = PREC ? uf[(size_t)r*64 + lane] : gbf(uh + (size_t)r*64 + lane);
      acc += fmaxf(z+vc, 0.f);
    }

    float mr = (deg > 0) ? acc/(float)deg : 0.f;
    sS[w][lane] = mr;                 // in-wave exchange; per-wave DS order
    const float4* s4 = reinterpret_cast<const float4*>(&sS[w][0]);
    float m = b2l;
    #pragma unroll
    for (int q = 0; q < 16; q++){
      float4 v4 = s4[q];
      m += v4.x*w2c[4*q+0] + v4.y*w2c[4*q+1] + v4.z*w2c[4*q+2] + v4.w*w2c[4*q+3];
    }
    if (deg == 0) m = 0.f;            // masked mean: isolated nodes -> 0 (no b2)
    if (PREC) aggf[(size_t)node*64 + lane] = m;
    else      aggh[(size_t)node*64 + lane] = f2bu(m);
  }
}

// ---------------- update MLP + tactical head ----------------
// agg pointers may alias `out` (config C): no __restrict__ on them or out.
__global__ __launch_bounds__(256, 2) void k_upd(
    const unsigned short* __restrict__ hb,  // [N,64] bf16
    const float* aggf, const unsigned short* aggh,
    const float* __restrict__ uW1,   // [128,64]
    const float* __restrict__ ub1,
    const float* __restrict__ uW2,   // [64,32]
    const float* __restrict__ ub2,
    const float* __restrict__ tW1,   // [32,64]
    const float* __restrict__ tb1,
    const float* __restrict__ tW2,   // [64,16]
    const float* __restrict__ tb2,
    const float* __restrict__ tW3,   // [16,4]
    const float* __restrict__ tb3,
    float* out,                       // [N*32] h2 then [N*4] tactical
    int N, int aggF32)
{
  __shared__ float uW1Ts[64*128];  // [j][k]
  __shared__ float uW2s[64*32];
  __shared__ float tW1s[32*64];
  __shared__ float tW2s[64*16];
  __shared__ float tW3s[16*4];
  __shared__ float ub1s[64], ub2s[32], tb1s[64], tb2s[16], tb3s[4];
  int tid = threadIdx.x;
  for (int i = tid; i < 128*64; i += 256){ int k = i >> 6, j = i & 63; uW1Ts[j*128 + k] = uW1[i]; }
  for (int i = tid; i < 64*32; i += 256) uW2s[i] = uW2[i];
  for (int i = tid; i < 32*64; i += 256) tW1s[i] = tW1[i];
  for (int i = tid; i < 64*16; i += 256) tW2s[i] = tW2[i];
  if (tid < 64){ ub1s[tid] = ub1[tid]; tb1s[tid] = tb1[tid]; tW3s[tid] = tW3[tid]; }
  if (tid < 32) ub2s[tid] = ub2[tid];
  if (tid < 16) tb2s[tid] = tb2[tid];
  if (tid < 4)  tb3s[tid] = tb3[tid];
  __syncthreads();
  int n = blockIdx.x * 256 + tid;
  if (n >= N) return;

  float feat[128];
  {
    const uint4* ha = reinterpret_cast<const uint4*>(hb + (size_t)n*64);
    #pragma unroll
    for (int q = 0; q < 8; q++) unpack8(ha[q], &feat[8*q]);
  }
  if (aggF32){
    const float4* sr = reinterpret_cast<const float4*>(aggf + (size_t)n*64);
    #pragma unroll
    for (int q = 0; q < 16; q++){
      float4 v = sr[q];
      feat[64+4*q+0]=v.x; feat[64+4*q+1]=v.y; feat[64+4*q+2]=v.z; feat[64+4*q+3]=v.w;
    }
  } else {
    const uint4* sr = reinterpret_cast<const uint4*>(aggh + (size_t)n*64);
    #pragma unroll
    for (int q = 0; q < 8; q++) unpack8(sr[q], &feat[64+8*q]);
  }

  float h2[32];
  #pragma unroll
  for (int m = 0; m < 32; m++) h2[m] = ub2s[m];

  #pragma unroll 1
  for (int j = 0; j < 64; j++){
    const float4* w1 = reinterpret_cast<const float4*>(&uW1Ts[j*128]);
    float s0 = 0.f, s1 = 0.f, s2 = 0.f, s3 = 0.f;
    #pragma unroll
    for (int q = 0; q < 32; q++){
      float4 w = w1[q];
      s0 += feat[4*q+0]*w.x; s1 += feat[4*q+1]*w.y;
      s2 += feat[4*q+2]*w.z; s3 += feat[4*q+3]*w.w;
    }
    float s = fmaxf((s0+s1) + (s2+s3) + ub1s[j], 0.f);
    const float4* w2 = reinterpret_cast<const float4*>(&uW2s[j*32]);
    #pragma unroll
    for (int q = 0; q < 8; q++){
      float4 w = w2[q];
      h2[4*q+0] += s*w.x; h2[4*q+1] += s*w.y; h2[4*q+2] += s*w.z; h2[4*q+3] += s*w.w;
    }
  }
  float4* o1 = reinterpret_cast<float4*>(out + (size_t)n*32);
  #pragma unroll
  for (int q = 0; q < 8; q++){
    float4 v;
    v.x = h2[4*q+0]; v.y = h2[4*q+1]; v.z = h2[4*q+2]; v.w = h2[4*q+3];
    o1[q] = v;
  }

  float t2[16];
  #pragma unroll
  for (int m = 0; m < 16; m++) t2[m] = 0.f;
  #pragma unroll 1
  for (int j = 0; j < 64; j++){
    float s = tb1s[j];
    #pragma unroll
    for (int k = 0; k < 32; k++) s += h2[k] * tW1s[k*64 + j];
    s = fmaxf(s, 0.f);
    #pragma unroll
    for (int m = 0; m < 16; m++) t2[m] += s * tW2s[j*16 + m];
  }
  float o[4];
  #pragma unroll
  for (int q = 0; q < 4; q++) o[q] = tb3s[q];
  #pragma unroll
  for (int m = 0; m < 16; m++){
    float tm = fmaxf(t2[m] + tb2s[m], 0.f);
    #pragma unroll
    for (int q = 0; q < 4; q++) o[q] += tm * tW3s[m*4 + q];
  }
  float4* o2 = reinterpret_cast<float4*>(out + (size_t)N*32 + (size_t)n*4);
  float4 vv; vv.x = o[0]; vv.y = o[1]; vv.z = o[2]; vv.w = o[3];
  *o2 = vv;
}

extern "C" void kernel_launch(void* const* d_in, const int* in_sizes, int n_in,
                              void* d_out, int out_size, void* d_ws, size_t ws_size,
                              hipStream_t stream)
{
  const float* x     = (const float*)d_in[0];
  const int*   ei    = (const int*)d_in[1];
  const float* encW1 = (const float*)d_in[2];
  const float* encb1 = (const float*)d_in[3];
  const float* encW2 = (const float*)d_in[4];
  const float* encb2 = (const float*)d_in[5];
  const float* msgW1 = (const float*)d_in[6];
  const float* msgb1 = (const float*)d_in[7];
  const float* msgW2 = (const float*)d_in[8];
  const float* msgb2 = (const float*)d_in[9];
  const float* updW1 = (const float*)d_in[10];
  const float* updb1 = (const float*)d_in[11];
  const float* updW2 = (const float*)d_in[12];
  const float* updb2 = (const float*)d_in[13];
  const float* tacW1 = (const float*)d_in[14];
  const float* tacb1 = (const float*)d_in[15];
  const float* tacW2 = (const float*)d_in[16];
  const float* tacb2 = (const float*)d_in[17];
  const float* tacW3 = (const float*)d_in[18];
  const float* tacb3 = (const float*)d_in[19];

  int N = in_sizes[0] / 6;
  int E = in_sizes[1] / 2;
  float* out = (float*)d_out;

  auto align = [](size_t v){ return (v + 255) & ~(size_t)255; };
  // common tail: counts(=cursor) [N] | offsets [N+1] | part [258] | list [E] | flag
  auto tail = [&](size_t o){
    o = align(o); o += (size_t)N*4;        // counts / cursor
    o = align(o); o += (size_t)(N+1)*4;    // offsets
    o = align(o); o += 258*4;              // part
    o = align(o); o += (size_t)E*4;        // list
    o = align(o); o += 4;                  // flag
    return o;
  };
  size_t hbB = (size_t)N*64*2;
  size_t totalA = tail(align(hbB) + (size_t)N*64*4*2);  // u,v f32 (agg aliases v)
  size_t totalB = tail(align(hbB) + (size_t)N*64*2*2);  // u,v bf16 (agg aliases v)

  int cfg = (ws_size >= totalA) ? 2 : (ws_size >= totalB) ? 1 : 0;  // 2=A,1=B,0=C
  int PREC  = (cfg == 2) ? 1 : 0;

  char* ws = (char*)d_ws;
  size_t o = 0;
  unsigned short* hb = (unsigned short*)(ws + o); o = align(o + hbB);
  float* uf = nullptr; unsigned short* uh = nullptr;
  float* vf = nullptr; unsigned short* vh = nullptr;
  if (cfg == 2){
    uf = (float*)(ws + o); o = align(o + (size_t)N*64*4);
    vf = (float*)(ws + o); o = align(o + (size_t)N*64*4);
  } else if (cfg == 1){
    uh = (unsigned short*)(ws + o); o = align(o + (size_t)N*64*2);
    vh = (unsigned short*)(ws + o); o = align(o + (size_t)N*64*2);
  } else {
    uh = (unsigned short*)(ws + o); o = align(o + (size_t)N*64*2);
    vh = (unsigned short*)out;                  // d_out scratch: first 6.4MB
  }
  o = align(o); int* counts  = (int*)(ws + o); o = align(o + (size_t)N*4);
  int* offsets = (int*)(ws + o); o = align(o + (size_t)(N+1)*4);
  int* part    = (int*)(ws + o); o = align(o + 258*4);
  int* list    = (int*)(ws + o); o = align(o + (size_t)E*4);
  int* flag    = (int*)(ws + o);
  int* cursor  = counts;  // counts dead after k_scan1

  hipMemsetAsync(counts, 0, (size_t)N*4, stream);

  dim3 blk(256);
  int nblkN = (N + 255) / 256;   // 196 (<=256 required by k_scan2)
  int nblkE = (E + 255) / 256;

  k_flag <<<dim3(1),     blk, 0, stream>>>(ei, flag, 8192);
  k_enc  <<<dim3(nblkN), blk, 0, stream>>>(x, encW1, encb1, encW2, encb2, hb, N);
  if (PREC) k_uv<1><<<dim3(2048), blk, 0, stream>>>(hb, msgW1, uf, uh, vf, vh, N);
  else      k_uv<0><<<dim3(2048), blk, 0, stream>>>(hb, msgW1, uf, uh, vf, vh, N);
  k_cnt  <<<dim3(nblkE), blk, 0, stream>>>(ei, flag, counts, E, N);
  k_scan1<<<dim3(nblkN), blk, 0, stream>>>(counts, offsets, part, N);
  k_scan2<<<dim3(1),     blk, 0, stream>>>(part, nblkN, offsets, N, E);
  k_scan3<<<dim3(nblkN), blk, 0, stream>>>(offsets, cursor, part, N);
  k_fill <<<dim3(nblkE), blk, 0, stream>>>(ei, flag, cursor, list, E, N);
  // agg output aliases v (safe: per-node v read by owner wave before agg write)
  if (PREC) k_agg<1><<<dim3(2048), blk, 0, stream>>>(uf, uh, vf, vh, vf, vh,
                                                     msgb1, msgW2, msgb2, offsets, list, N);
  else      k_agg<0><<<dim3(2048), blk, 0, stream>>>(uf, uh, vf, vh, vf, vh,
                                                     msgb1, msgW2, msgb2, offsets, list, N);
  k_upd  <<<dim3(nblkN), blk, 0, stream>>>(hb, vf, vh,
                                           updW1, updb1, updW2, updb2,
                                           tacW1, tacb1, tacW2, tacb2, tacW3, tacb3,
                                           out, N, PREC);
}